// Round 1
// baseline (616.169 us; speedup 1.0000x reference)
//
#include <hip/hip_runtime.h>

// GCN link predictor: z1 = relu(GCNConv(x,W1,b1)); z2 = GCNConv(z1,W2,b2);
// out[e] = dot(z2[src[e]], z2[dst[e]])
// Strategy: CSR-by-dst build (no float atomics), fp32 register-tiled GEMM,
// per-node aggregation, per-wave edge decode.

#define THREADS 256

// ---------- degree ----------
__global__ __launch_bounds__(256) void deg_kernel(const int* __restrict__ dst,
                                                  int* __restrict__ deg, int E) {
  int e = blockIdx.x * 256 + threadIdx.x;
  if (e < E) atomicAdd(&deg[dst[e]], 1);
}

__global__ __launch_bounds__(256) void dinv_kernel(const int* __restrict__ deg,
                                                   float* __restrict__ dinv, int N) {
  int i = blockIdx.x * 256 + threadIdx.x;
  if (i < N) dinv[i] = rsqrtf((float)(deg[i] + 1));  // +1 self loop
}

// ---------- block scan (512 elems/block) ----------
__global__ __launch_bounds__(512) void scan1_kernel(const int* __restrict__ in,
                                                    int* __restrict__ tmp,
                                                    int* __restrict__ bsums, int n) {
  __shared__ int sm[2][512];
  int t = threadIdx.x;
  int gid = blockIdx.x * 512 + t;
  int v = (gid < n) ? in[gid] : 0;
  int pp = 0;
  sm[0][t] = v;
  __syncthreads();
  for (int off = 1; off < 512; off <<= 1) {
    int nv = sm[pp][t];
    if (t >= off) nv += sm[pp][t - off];
    sm[pp ^ 1][t] = nv;
    pp ^= 1;
    __syncthreads();
  }
  int inc = sm[pp][t];
  if (gid < n) tmp[gid] = inc;
  if (t == 511) bsums[blockIdx.x] = inc;
}

__global__ __launch_bounds__(256) void scan2_kernel(int* bsums, int nb) {
  __shared__ int sm[2][256];
  int t = threadIdx.x;
  int v = (t < nb) ? bsums[t] : 0;
  int pp = 0;
  sm[0][t] = v;
  __syncthreads();
  for (int off = 1; off < 256; off <<= 1) {
    int nv = sm[pp][t];
    if (t >= off) nv += sm[pp][t - off];
    sm[pp ^ 1][t] = nv;
    pp ^= 1;
    __syncthreads();
  }
  int inc = sm[pp][t];
  if (t < nb) bsums[t] = inc - v;  // exclusive
}

__global__ __launch_bounds__(256) void scan3_kernel(const int* __restrict__ tmp,
                                                    const int* __restrict__ bsums,
                                                    int* __restrict__ rowptr, int n) {
  int gid = blockIdx.x * 256 + threadIdx.x;
  if (gid < n) rowptr[gid + 1] = tmp[gid] + bsums[gid >> 9];
  if (gid == 0) rowptr[0] = 0;
}

__global__ __launch_bounds__(256) void scatter_kernel(const int* __restrict__ src,
                                                      const int* __restrict__ dst,
                                                      const int* __restrict__ rowptr,
                                                      int* __restrict__ cnt,
                                                      int* __restrict__ csr, int E) {
  int e = blockIdx.x * 256 + threadIdx.x;
  if (e < E) {
    int d = dst[e];
    int pos = rowptr[d] + atomicAdd(&cnt[d], 1);
    csr[pos] = src[e];
  }
}

// ---------- fp32 GEMM: out[M,128] = A[M,128] @ W[128,128] ----------
// 64 rows/block, 256 threads, thread tile 8 rows x 4 cols, K-tiles of 32.
// LDS: W tile 16KB + x-transposed tile (pad 68) 8.5KB.
__global__ __launch_bounds__(256) void gemm_kernel(const float* __restrict__ A,
                                                   const float* __restrict__ W,
                                                   float* __restrict__ out, int M) {
  __shared__ float4 Ws4[32 * 32];  // [k][cq]  (k-tile of 32)
  __shared__ float xs[32 * 68];    // [k][row], pad 68 to break bank conflicts
  const float4* A4 = (const float4*)A;
  const float4* W4 = (const float4*)W;
  float4* out4 = (float4*)out;

  int tid = threadIdx.x;
  int row_base = blockIdx.x * 64;
  int cg = tid & 31;          // col group: cols 4*cg .. 4*cg+3
  int rq = (tid >> 5) * 2;    // float4 index of r0 = 8*(tid>>5)

  float4 acc[8];
#pragma unroll
  for (int i = 0; i < 8; ++i) acc[i] = make_float4(0.f, 0.f, 0.f, 0.f);

#pragma unroll 1
  for (int kt = 0; kt < 4; ++kt) {
    // stage W k-tile: 32x128 floats = 1024 float4
#pragma unroll
    for (int i = 0; i < 4; ++i) {
      int g = tid + i * 256;
      Ws4[g] = W4[kt * 1024 + g];
    }
    // stage x tile transposed: 64 rows x 32 k
#pragma unroll
    for (int i = 0; i < 2; ++i) {
      int f = tid + i * 256;     // 512 float4s
      int row = f >> 3;          // 0..63
      int kq = f & 7;            // float4 within the 32-k tile
      float4 v = make_float4(0.f, 0.f, 0.f, 0.f);
      int grow = row_base + row;
      if (grow < M) v = A4[grow * 32 + kt * 8 + kq];
      xs[(4 * kq + 0) * 68 + row] = v.x;
      xs[(4 * kq + 1) * 68 + row] = v.y;
      xs[(4 * kq + 2) * 68 + row] = v.z;
      xs[(4 * kq + 3) * 68 + row] = v.w;
    }
    __syncthreads();

    const float4* xs4 = (const float4*)xs;
#pragma unroll
    for (int k = 0; k < 32; ++k) {
      float4 w = Ws4[k * 32 + cg];
      float4 xa = xs4[k * 17 + rq];
      float4 xb = xs4[k * 17 + rq + 1];
      float xr[8] = {xa.x, xa.y, xa.z, xa.w, xb.x, xb.y, xb.z, xb.w};
#pragma unroll
      for (int rr = 0; rr < 8; ++rr) {
        acc[rr].x = fmaf(xr[rr], w.x, acc[rr].x);
        acc[rr].y = fmaf(xr[rr], w.y, acc[rr].y);
        acc[rr].z = fmaf(xr[rr], w.z, acc[rr].z);
        acc[rr].w = fmaf(xr[rr], w.w, acc[rr].w);
      }
    }
    __syncthreads();
  }

#pragma unroll
  for (int rr = 0; rr < 8; ++rr) {
    int row = row_base + (tid >> 5) * 8 + rr;
    if (row < M) out4[row * 32 + cg] = acc[rr];
  }
}

// ---------- aggregation: out[i] = dinv[i]*(dinv[i]*xw[i] + sum_j dinv[j]*xw[j]) + b
__global__ __launch_bounds__(256) void agg_kernel(const float* __restrict__ xw,
                                                  const float* __restrict__ dinv,
                                                  const int* __restrict__ rowptr,
                                                  const int* __restrict__ csr,
                                                  const float* __restrict__ bias,
                                                  float* __restrict__ out,
                                                  int relu, int N) {
  int node = blockIdx.x * 2 + (threadIdx.x >> 7);
  int t = threadIdx.x & 127;
  if (node >= N) return;
  float di = dinv[node];
  float acc = di * xw[node * 128 + t];
  int s = rowptr[node], e = rowptr[node + 1];
  for (int k = s; k < e; ++k) {
    int j = csr[k];
    acc += dinv[j] * xw[j * 128 + t];
  }
  float v = di * acc + bias[t];
  if (relu) v = fmaxf(v, 0.f);
  out[node * 128 + t] = v;
}

// ---------- decode: one wave per edge ----------
__global__ __launch_bounds__(256) void decode_kernel(const float* __restrict__ z,
                                                     const int* __restrict__ src,
                                                     const int* __restrict__ dst,
                                                     float* __restrict__ out, int E) {
  int e = blockIdx.x * 4 + (threadIdx.x >> 6);
  int l = threadIdx.x & 63;
  if (e >= E) return;
  int s = src[e], d = dst[e];
  const float2* z2 = (const float2*)z;
  float2 a = z2[s * 64 + l];
  float2 b = z2[d * 64 + l];
  float p = a.x * b.x + a.y * b.y;
#pragma unroll
  for (int off = 32; off > 0; off >>= 1) p += __shfl_xor(p, off);
  if (l == 0) out[e] = p;
}

extern "C" void kernel_launch(void* const* d_in, const int* in_sizes, int n_in,
                              void* d_out, int out_size, void* d_ws, size_t ws_size,
                              hipStream_t stream) {
  const float* x  = (const float*)d_in[0];
  const int*   ei = (const int*)d_in[1];
  const float* W1 = (const float*)d_in[2];
  const float* b1 = (const float*)d_in[3];
  const float* W2 = (const float*)d_in[4];
  const float* b2 = (const float*)d_in[5];

  const int N = in_sizes[0] / 128;
  const int E = in_sizes[1] / 2;
  const int* src = ei;
  const int* dst = ei + E;

  // workspace carve-up (256B aligned)
  char* ws = (char*)d_ws;
  size_t off = 0;
  auto alloc = [&](size_t bytes) -> void* {
    void* p = ws + off;
    off += (bytes + 255) & ~(size_t)255;
    return p;
  };
  float* bufA   = (float*)alloc((size_t)N * 128 * 4);
  float* bufB   = (float*)alloc((size_t)N * 128 * 4);
  float* dinv   = (float*)alloc((size_t)N * 4);
  int*   rowptr = (int*)alloc((size_t)(N + 1) * 4);
  int*   csr    = (int*)alloc((size_t)E * 4);
  int*   tmp    = (int*)alloc((size_t)N * 4);
  int*   deg    = (int*)alloc((size_t)N * 4);   // zeroed region starts here
  int*   cnt    = (int*)alloc((size_t)N * 4);
  int*   bsums  = (int*)alloc(1024);
  size_t zbytes = ((char*)bsums + 1024) - (char*)deg;
  hipMemsetAsync(deg, 0, zbytes, stream);

  const int EB = (E + 255) / 256;
  const int NB = (N + 255) / 256;
  const int SB = (N + 511) / 512;  // 196 for N=100000, fits in one scan2 block

  // degree + dinv
  deg_kernel<<<EB, 256, 0, stream>>>(dst, deg, E);
  dinv_kernel<<<NB, 256, 0, stream>>>(deg, dinv, N);

  // CSR build: exclusive scan of deg -> rowptr, then scatter
  scan1_kernel<<<SB, 512, 0, stream>>>(deg, tmp, bsums, N);
  scan2_kernel<<<1, 256, 0, stream>>>(bsums, SB);
  scan3_kernel<<<NB, 256, 0, stream>>>(tmp, bsums, rowptr, N);
  scatter_kernel<<<EB, 256, 0, stream>>>(src, dst, rowptr, cnt, csr, E);

  const int GB = (N + 63) / 64;
  const int AB = (N + 1) / 2;
  const int DB = (E + 3) / 4;

  // layer 1
  gemm_kernel<<<GB, 256, 0, stream>>>(x, W1, bufA, N);
  agg_kernel<<<AB, 256, 0, stream>>>(bufA, dinv, rowptr, csr, b1, bufB, 1, N);
  // layer 2
  gemm_kernel<<<GB, 256, 0, stream>>>(bufB, W2, bufA, N);
  agg_kernel<<<AB, 256, 0, stream>>>(bufA, dinv, rowptr, csr, b2, bufB, 0, N);
  // decode
  decode_kernel<<<DB, 256, 0, stream>>>(bufB, src, dst, (float*)d_out, E);
}

// Round 3
// 428.973 us; speedup vs baseline: 1.4364x; 1.4364x over previous
//
#include <hip/hip_runtime.h>

// GCN link predictor: z1 = relu(GCNConv(x,W1,b1)); z2 = GCNConv(z1,W2,b2);
// out[e] = dot(z2[src[e]], z2[dst[e]])
// R1: dinv folded into GEMM epilogue (agg inner loop is pure adds);
//     agg = 32 lanes/node, float4, neighbor loop unrolled x4 (MLP);
//     decode = 32 lanes/edge, float4, shuffle reduce.
// R2: resubmit unchanged (previous bench was an infra failure, not a kernel error).

// ---------- degree ----------
__global__ __launch_bounds__(256) void deg_kernel(const int* __restrict__ dst,
                                                  int* __restrict__ deg, int E) {
  int e = blockIdx.x * 256 + threadIdx.x;
  if (e < E) atomicAdd(&deg[dst[e]], 1);
}

// ---------- block scan (512 elems/block) ----------
__global__ __launch_bounds__(512) void scan1_kernel(const int* __restrict__ in,
                                                    int* __restrict__ tmp,
                                                    int* __restrict__ bsums, int n) {
  __shared__ int sm[2][512];
  int t = threadIdx.x;
  int gid = blockIdx.x * 512 + t;
  int v = (gid < n) ? in[gid] : 0;
  int pp = 0;
  sm[0][t] = v;
  __syncthreads();
  for (int off = 1; off < 512; off <<= 1) {
    int nv = sm[pp][t];
    if (t >= off) nv += sm[pp][t - off];
    sm[pp ^ 1][t] = nv;
    pp ^= 1;
    __syncthreads();
  }
  int inc = sm[pp][t];
  if (gid < n) tmp[gid] = inc;
  if (t == 511) bsums[blockIdx.x] = inc;
}

__global__ __launch_bounds__(256) void scan2_kernel(int* bsums, int nb) {
  __shared__ int sm[2][256];
  int t = threadIdx.x;
  int v = (t < nb) ? bsums[t] : 0;
  int pp = 0;
  sm[0][t] = v;
  __syncthreads();
  for (int off = 1; off < 256; off <<= 1) {
    int nv = sm[pp][t];
    if (t >= off) nv += sm[pp][t - off];
    sm[pp ^ 1][t] = nv;
    pp ^= 1;
    __syncthreads();
  }
  int inc = sm[pp][t];
  if (t < nb) bsums[t] = inc - v;  // exclusive
}

// rowptr from scan, plus dinv = rsqrt(deg+1) fused here (saves a launch)
__global__ __launch_bounds__(256) void scan3_kernel(const int* __restrict__ tmp,
                                                    const int* __restrict__ bsums,
                                                    const int* __restrict__ deg,
                                                    int* __restrict__ rowptr,
                                                    float* __restrict__ dinv, int n) {
  int gid = blockIdx.x * 256 + threadIdx.x;
  if (gid < n) {
    rowptr[gid + 1] = tmp[gid] + bsums[gid >> 9];
    dinv[gid] = rsqrtf((float)(deg[gid] + 1));  // +1 self loop
  }
  if (gid == 0) rowptr[0] = 0;
}

__global__ __launch_bounds__(256) void scatter_kernel(const int* __restrict__ src,
                                                      const int* __restrict__ dst,
                                                      const int* __restrict__ rowptr,
                                                      int* __restrict__ cnt,
                                                      int* __restrict__ csr, int E) {
  int e = blockIdx.x * 256 + threadIdx.x;
  if (e < E) {
    int d = dst[e];
    int pos = rowptr[d] + atomicAdd(&cnt[d], 1);
    csr[pos] = src[e];
  }
}

// ---------- fp32 GEMM: out[r,:] = dinv[r] * (A[r,:] @ W)  (dinv prescale fused)
// 64 rows/block, 256 threads, thread tile 8 rows x 4 cols, K-tiles of 32.
__global__ __launch_bounds__(256) void gemm_kernel(const float* __restrict__ A,
                                                   const float* __restrict__ W,
                                                   const float* __restrict__ dinv,
                                                   float* __restrict__ out, int M) {
  __shared__ float4 Ws4[32 * 32];  // [k][cq]
  __shared__ float xs[32 * 68];    // [k][row], pad 68
  const float4* A4 = (const float4*)A;
  const float4* W4 = (const float4*)W;
  float4* out4 = (float4*)out;

  int tid = threadIdx.x;
  int row_base = blockIdx.x * 64;
  int cg = tid & 31;
  int rq = (tid >> 5) * 2;

  float4 acc[8];
#pragma unroll
  for (int i = 0; i < 8; ++i) acc[i] = make_float4(0.f, 0.f, 0.f, 0.f);

#pragma unroll 1
  for (int kt = 0; kt < 4; ++kt) {
#pragma unroll
    for (int i = 0; i < 4; ++i) {
      int g = tid + i * 256;
      Ws4[g] = W4[kt * 1024 + g];
    }
#pragma unroll
    for (int i = 0; i < 2; ++i) {
      int f = tid + i * 256;
      int row = f >> 3;
      int kq = f & 7;
      float4 v = make_float4(0.f, 0.f, 0.f, 0.f);
      int grow = row_base + row;
      if (grow < M) v = A4[grow * 32 + kt * 8 + kq];
      xs[(4 * kq + 0) * 68 + row] = v.x;
      xs[(4 * kq + 1) * 68 + row] = v.y;
      xs[(4 * kq + 2) * 68 + row] = v.z;
      xs[(4 * kq + 3) * 68 + row] = v.w;
    }
    __syncthreads();

    const float4* xs4 = (const float4*)xs;
#pragma unroll
    for (int k = 0; k < 32; ++k) {
      float4 w = Ws4[k * 32 + cg];
      float4 xa = xs4[k * 17 + rq];
      float4 xb = xs4[k * 17 + rq + 1];
      float xr[8] = {xa.x, xa.y, xa.z, xa.w, xb.x, xb.y, xb.z, xb.w};
#pragma unroll
      for (int rr = 0; rr < 8; ++rr) {
        acc[rr].x = fmaf(xr[rr], w.x, acc[rr].x);
        acc[rr].y = fmaf(xr[rr], w.y, acc[rr].y);
        acc[rr].z = fmaf(xr[rr], w.z, acc[rr].z);
        acc[rr].w = fmaf(xr[rr], w.w, acc[rr].w);
      }
    }
    __syncthreads();
  }

#pragma unroll
  for (int rr = 0; rr < 8; ++rr) {
    int row = row_base + (tid >> 5) * 8 + rr;
    if (row < M) {
      float di = dinv[row];
      float4 a = acc[rr];
      a.x *= di; a.y *= di; a.z *= di; a.w *= di;
      out4[row * 32 + cg] = a;
    }
  }
}

// ---------- aggregation over prescaled rows ----------
// out[i] = dinv[i] * (xw_s[i] + sum_{j in N(i)} xw_s[j]) + b   (xw_s = dinv-prescaled)
// 32 lanes per node, float4 per lane, neighbor loop unrolled x4 for MLP.
__global__ __launch_bounds__(256) void agg_kernel(const float4* __restrict__ xw4,
                                                  const float* __restrict__ dinv,
                                                  const int* __restrict__ rowptr,
                                                  const int* __restrict__ csr,
                                                  const float4* __restrict__ bias4,
                                                  float4* __restrict__ out4,
                                                  int relu, int N) {
  int node = blockIdx.x * 8 + (threadIdx.x >> 5);
  int l = threadIdx.x & 31;
  if (node >= N) return;
  float4 acc = xw4[node * 32 + l];  // self loop (prescaled)
  int s = rowptr[node], e = rowptr[node + 1];
  int k = s;
  for (; k + 4 <= e; k += 4) {
    int j0 = csr[k], j1 = csr[k + 1], j2 = csr[k + 2], j3 = csr[k + 3];
    float4 v0 = xw4[j0 * 32 + l];
    float4 v1 = xw4[j1 * 32 + l];
    float4 v2 = xw4[j2 * 32 + l];
    float4 v3 = xw4[j3 * 32 + l];
    acc.x += (v0.x + v1.x) + (v2.x + v3.x);
    acc.y += (v0.y + v1.y) + (v2.y + v3.y);
    acc.z += (v0.z + v1.z) + (v2.z + v3.z);
    acc.w += (v0.w + v1.w) + (v2.w + v3.w);
  }
  for (; k < e; ++k) {
    int j = csr[k];
    float4 v = xw4[j * 32 + l];
    acc.x += v.x; acc.y += v.y; acc.z += v.z; acc.w += v.w;
  }
  float di = dinv[node];
  float4 bb = bias4[l];
  float4 o;
  o.x = fmaf(di, acc.x, bb.x);
  o.y = fmaf(di, acc.y, bb.y);
  o.z = fmaf(di, acc.z, bb.z);
  o.w = fmaf(di, acc.w, bb.w);
  if (relu) {
    o.x = fmaxf(o.x, 0.f); o.y = fmaxf(o.y, 0.f);
    o.z = fmaxf(o.z, 0.f); o.w = fmaxf(o.w, 0.f);
  }
  out4[node * 32 + l] = o;
}

// ---------- decode: 32 lanes per edge, float4 ----------
__global__ __launch_bounds__(256) void decode_kernel(const float4* __restrict__ z4,
                                                     const int* __restrict__ src,
                                                     const int* __restrict__ dst,
                                                     float* __restrict__ out, int E) {
  int e = blockIdx.x * 8 + (threadIdx.x >> 5);
  int r = threadIdx.x & 31;
  if (e >= E) return;
  int s = src[e], d = dst[e];
  float4 a = z4[s * 32 + r];
  float4 b = z4[d * 32 + r];
  float p = a.x * b.x + a.y * b.y + a.z * b.z + a.w * b.w;
#pragma unroll
  for (int off = 16; off > 0; off >>= 1) p += __shfl_xor(p, off);
  if (r == 0) out[e] = p;
}

extern "C" void kernel_launch(void* const* d_in, const int* in_sizes, int n_in,
                              void* d_out, int out_size, void* d_ws, size_t ws_size,
                              hipStream_t stream) {
  const float* x  = (const float*)d_in[0];
  const int*   ei = (const int*)d_in[1];
  const float* W1 = (const float*)d_in[2];
  const float* b1 = (const float*)d_in[3];
  const float* W2 = (const float*)d_in[4];
  const float* b2 = (const float*)d_in[5];

  const int N = in_sizes[0] / 128;
  const int E = in_sizes[1] / 2;
  const int* src = ei;
  const int* dst = ei + E;

  char* ws = (char*)d_ws;
  size_t off = 0;
  auto alloc = [&](size_t bytes) -> void* {
    void* p = ws + off;
    off += (bytes + 255) & ~(size_t)255;
    return p;
  };
  float* bufA   = (float*)alloc((size_t)N * 128 * 4);
  float* bufB   = (float*)alloc((size_t)N * 128 * 4);
  float* dinv   = (float*)alloc((size_t)N * 4);
  int*   rowptr = (int*)alloc((size_t)(N + 1) * 4);
  int*   csr    = (int*)alloc((size_t)E * 4);
  int*   tmp    = (int*)alloc((size_t)N * 4);
  int*   deg    = (int*)alloc((size_t)N * 4);   // zeroed region starts here
  int*   cnt    = (int*)alloc((size_t)N * 4);
  int*   bsums  = (int*)alloc(1024);
  size_t zbytes = ((char*)bsums + 1024) - (char*)deg;
  hipMemsetAsync(deg, 0, zbytes, stream);

  const int EB = (E + 255) / 256;
  const int NB = (N + 255) / 256;
  const int SB = (N + 511) / 512;

  deg_kernel<<<EB, 256, 0, stream>>>(dst, deg, E);
  scan1_kernel<<<SB, 512, 0, stream>>>(deg, tmp, bsums, N);
  scan2_kernel<<<1, 256, 0, stream>>>(bsums, SB);
  scan3_kernel<<<NB, 256, 0, stream>>>(tmp, bsums, deg, rowptr, dinv, N);
  scatter_kernel<<<EB, 256, 0, stream>>>(src, dst, rowptr, cnt, csr, E);

  const int GB = (N + 63) / 64;
  const int AB = (N + 7) / 8;
  const int DB = (E + 7) / 8;

  // layer 1
  gemm_kernel<<<GB, 256, 0, stream>>>(x, W1, dinv, bufA, N);
  agg_kernel<<<AB, 256, 0, stream>>>((const float4*)bufA, dinv, rowptr, csr,
                                     (const float4*)b1, (float4*)bufB, 1, N);
  // layer 2
  gemm_kernel<<<GB, 256, 0, stream>>>(bufB, W2, dinv, bufA, N);
  agg_kernel<<<AB, 256, 0, stream>>>((const float4*)bufA, dinv, rowptr, csr,
                                     (const float4*)b2, (float4*)bufB, 0, N);
  // decode
  decode_kernel<<<DB, 256, 0, stream>>>((const float4*)bufB, src, dst,
                                        (float*)d_out, E);
}

// Round 5
// 422.909 us; speedup vs baseline: 1.4570x; 1.0143x over previous
//
#include <hip/hip_runtime.h>

// GCN link predictor: z1 = relu(GCNConv(x,W1,b1)); z2 = GCNConv(z1,W2,b2);
// out[e] = dot(z2[src[e]], z2[dst[e]])
// R1: dinv folded into GEMM epilogue; agg 32 lanes/node float4 unroll x4;
//     decode 32 lanes/edge float4.
// R3: decode restructured over dst-CSR — z2[dst] held in registers, reused
//     across incident edges (halves gather bytes); agg now 16 lanes/node x
//     2 float4 (8 loads in flight/lane).
// R4: resubmit unchanged (R3 bench was an infra failure, not a kernel error).

// ---------- degree ----------
__global__ __launch_bounds__(256) void deg_kernel(const int* __restrict__ dst,
                                                  int* __restrict__ deg, int E) {
  int e = blockIdx.x * 256 + threadIdx.x;
  if (e < E) atomicAdd(&deg[dst[e]], 1);
}

// ---------- block scan (512 elems/block) ----------
__global__ __launch_bounds__(512) void scan1_kernel(const int* __restrict__ in,
                                                    int* __restrict__ tmp,
                                                    int* __restrict__ bsums, int n) {
  __shared__ int sm[2][512];
  int t = threadIdx.x;
  int gid = blockIdx.x * 512 + t;
  int v = (gid < n) ? in[gid] : 0;
  int pp = 0;
  sm[0][t] = v;
  __syncthreads();
  for (int off = 1; off < 512; off <<= 1) {
    int nv = sm[pp][t];
    if (t >= off) nv += sm[pp][t - off];
    sm[pp ^ 1][t] = nv;
    pp ^= 1;
    __syncthreads();
  }
  int inc = sm[pp][t];
  if (gid < n) tmp[gid] = inc;
  if (t == 511) bsums[blockIdx.x] = inc;
}

__global__ __launch_bounds__(256) void scan2_kernel(int* bsums, int nb) {
  __shared__ int sm[2][256];
  int t = threadIdx.x;
  int v = (t < nb) ? bsums[t] : 0;
  int pp = 0;
  sm[0][t] = v;
  __syncthreads();
  for (int off = 1; off < 256; off <<= 1) {
    int nv = sm[pp][t];
    if (t >= off) nv += sm[pp][t - off];
    sm[pp ^ 1][t] = nv;
    pp ^= 1;
    __syncthreads();
  }
  int inc = sm[pp][t];
  if (t < nb) bsums[t] = inc - v;  // exclusive
}

// rowptr from scan, plus dinv = rsqrt(deg+1) fused here
__global__ __launch_bounds__(256) void scan3_kernel(const int* __restrict__ tmp,
                                                    const int* __restrict__ bsums,
                                                    const int* __restrict__ deg,
                                                    int* __restrict__ rowptr,
                                                    float* __restrict__ dinv, int n) {
  int gid = blockIdx.x * 256 + threadIdx.x;
  if (gid < n) {
    rowptr[gid + 1] = tmp[gid] + bsums[gid >> 9];
    dinv[gid] = rsqrtf((float)(deg[gid] + 1));  // +1 self loop
  }
  if (gid == 0) rowptr[0] = 0;
}

// CSR scatter: store src AND edge id (decode needs eid for output slot)
__global__ __launch_bounds__(256) void scatter_kernel(const int* __restrict__ src,
                                                      const int* __restrict__ dst,
                                                      const int* __restrict__ rowptr,
                                                      int* __restrict__ cnt,
                                                      int* __restrict__ csr_src,
                                                      int* __restrict__ csr_eid, int E) {
  int e = blockIdx.x * 256 + threadIdx.x;
  if (e < E) {
    int d = dst[e];
    int pos = rowptr[d] + atomicAdd(&cnt[d], 1);
    csr_src[pos] = src[e];
    csr_eid[pos] = e;
  }
}

// ---------- fp32 GEMM: out[r,:] = dinv[r] * (A[r,:] @ W) ----------
__global__ __launch_bounds__(256) void gemm_kernel(const float* __restrict__ A,
                                                   const float* __restrict__ W,
                                                   const float* __restrict__ dinv,
                                                   float* __restrict__ out, int M) {
  __shared__ float4 Ws4[32 * 32];  // [k][cq]
  __shared__ float xs[32 * 68];    // [k][row], pad 68
  const float4* A4 = (const float4*)A;
  const float4* W4 = (const float4*)W;
  float4* out4 = (float4*)out;

  int tid = threadIdx.x;
  int row_base = blockIdx.x * 64;
  int cg = tid & 31;
  int rq = (tid >> 5) * 2;

  float4 acc[8];
#pragma unroll
  for (int i = 0; i < 8; ++i) acc[i] = make_float4(0.f, 0.f, 0.f, 0.f);

#pragma unroll 1
  for (int kt = 0; kt < 4; ++kt) {
#pragma unroll
    for (int i = 0; i < 4; ++i) {
      int g = tid + i * 256;
      Ws4[g] = W4[kt * 1024 + g];
    }
#pragma unroll
    for (int i = 0; i < 2; ++i) {
      int f = tid + i * 256;
      int row = f >> 3;
      int kq = f & 7;
      float4 v = make_float4(0.f, 0.f, 0.f, 0.f);
      int grow = row_base + row;
      if (grow < M) v = A4[grow * 32 + kt * 8 + kq];
      xs[(4 * kq + 0) * 68 + row] = v.x;
      xs[(4 * kq + 1) * 68 + row] = v.y;
      xs[(4 * kq + 2) * 68 + row] = v.z;
      xs[(4 * kq + 3) * 68 + row] = v.w;
    }
    __syncthreads();

    const float4* xs4 = (const float4*)xs;
#pragma unroll
    for (int k = 0; k < 32; ++k) {
      float4 w = Ws4[k * 32 + cg];
      float4 xa = xs4[k * 17 + rq];
      float4 xb = xs4[k * 17 + rq + 1];
      float xr[8] = {xa.x, xa.y, xa.z, xa.w, xb.x, xb.y, xb.z, xb.w};
#pragma unroll
      for (int rr = 0; rr < 8; ++rr) {
        acc[rr].x = fmaf(xr[rr], w.x, acc[rr].x);
        acc[rr].y = fmaf(xr[rr], w.y, acc[rr].y);
        acc[rr].z = fmaf(xr[rr], w.z, acc[rr].z);
        acc[rr].w = fmaf(xr[rr], w.w, acc[rr].w);
      }
    }
    __syncthreads();
  }

#pragma unroll
  for (int rr = 0; rr < 8; ++rr) {
    int row = row_base + (tid >> 5) * 8 + rr;
    if (row < M) {
      float di = dinv[row];
      float4 a = acc[rr];
      a.x *= di; a.y *= di; a.z *= di; a.w *= di;
      out4[row * 32 + cg] = a;
    }
  }
}

// ---------- aggregation over prescaled rows ----------
// 16 lanes/node, 2 float4 per lane, neighbor unroll x4 -> 8 loads in flight.
__global__ __launch_bounds__(256) void agg_kernel(const float4* __restrict__ xw4,
                                                  const float* __restrict__ dinv,
                                                  const int* __restrict__ rowptr,
                                                  const int* __restrict__ csr,
                                                  const float4* __restrict__ bias4,
                                                  float4* __restrict__ out4,
                                                  int relu, int N) {
  int node = blockIdx.x * 16 + (threadIdx.x >> 4);
  int l = threadIdx.x & 15;
  if (node >= N) return;
  float4 acc0 = xw4[node * 32 + l];        // self loop (prescaled)
  float4 acc1 = xw4[node * 32 + l + 16];
  int s = rowptr[node], e = rowptr[node + 1];
  int k = s;
  for (; k + 4 <= e; k += 4) {
    int j0 = csr[k], j1 = csr[k + 1], j2 = csr[k + 2], j3 = csr[k + 3];
    float4 a0 = xw4[j0 * 32 + l];
    float4 b0 = xw4[j0 * 32 + l + 16];
    float4 a1 = xw4[j1 * 32 + l];
    float4 b1 = xw4[j1 * 32 + l + 16];
    float4 a2 = xw4[j2 * 32 + l];
    float4 b2 = xw4[j2 * 32 + l + 16];
    float4 a3 = xw4[j3 * 32 + l];
    float4 b3 = xw4[j3 * 32 + l + 16];
    acc0.x += (a0.x + a1.x) + (a2.x + a3.x);
    acc0.y += (a0.y + a1.y) + (a2.y + a3.y);
    acc0.z += (a0.z + a1.z) + (a2.z + a3.z);
    acc0.w += (a0.w + a1.w) + (a2.w + a3.w);
    acc1.x += (b0.x + b1.x) + (b2.x + b3.x);
    acc1.y += (b0.y + b1.y) + (b2.y + b3.y);
    acc1.z += (b0.z + b1.z) + (b2.z + b3.z);
    acc1.w += (b0.w + b1.w) + (b2.w + b3.w);
  }
  for (; k < e; ++k) {
    int j = csr[k];
    float4 a = xw4[j * 32 + l];
    float4 b = xw4[j * 32 + l + 16];
    acc0.x += a.x; acc0.y += a.y; acc0.z += a.z; acc0.w += a.w;
    acc1.x += b.x; acc1.y += b.y; acc1.z += b.z; acc1.w += b.w;
  }
  float di = dinv[node];
  float4 bb0 = bias4[l];
  float4 bb1 = bias4[l + 16];
  float4 o0, o1;
  o0.x = fmaf(di, acc0.x, bb0.x); o0.y = fmaf(di, acc0.y, bb0.y);
  o0.z = fmaf(di, acc0.z, bb0.z); o0.w = fmaf(di, acc0.w, bb0.w);
  o1.x = fmaf(di, acc1.x, bb1.x); o1.y = fmaf(di, acc1.y, bb1.y);
  o1.z = fmaf(di, acc1.z, bb1.z); o1.w = fmaf(di, acc1.w, bb1.w);
  if (relu) {
    o0.x = fmaxf(o0.x, 0.f); o0.y = fmaxf(o0.y, 0.f);
    o0.z = fmaxf(o0.z, 0.f); o0.w = fmaxf(o0.w, 0.f);
    o1.x = fmaxf(o1.x, 0.f); o1.y = fmaxf(o1.y, 0.f);
    o1.z = fmaxf(o1.z, 0.f); o1.w = fmaxf(o1.w, 0.f);
  }
  out4[node * 32 + l] = o0;
  out4[node * 32 + l + 16] = o1;
}

// ---------- decode over dst-CSR: z2[dst] in registers, reused per edge ----
// 32 lanes per dst node; per neighbor one 512B gather (src row) instead of two.
__global__ __launch_bounds__(256) void decode_kernel(const float4* __restrict__ z4,
                                                     const int* __restrict__ rowptr,
                                                     const int* __restrict__ csr_src,
                                                     const int* __restrict__ csr_eid,
                                                     float* __restrict__ out, int N) {
  int node = blockIdx.x * 8 + (threadIdx.x >> 5);
  int l = threadIdx.x & 31;
  if (node >= N) return;
  float4 zd = z4[node * 32 + l];  // held in registers across all incident edges
  int s = rowptr[node], e = rowptr[node + 1];
  int k = s;
  for (; k + 4 <= e; k += 4) {
    int j0 = csr_src[k], j1 = csr_src[k + 1];
    int j2 = csr_src[k + 2], j3 = csr_src[k + 3];
    float4 v0 = z4[j0 * 32 + l];
    float4 v1 = z4[j1 * 32 + l];
    float4 v2 = z4[j2 * 32 + l];
    float4 v3 = z4[j3 * 32 + l];
    float p0 = zd.x * v0.x + zd.y * v0.y + zd.z * v0.z + zd.w * v0.w;
    float p1 = zd.x * v1.x + zd.y * v1.y + zd.z * v1.z + zd.w * v1.w;
    float p2 = zd.x * v2.x + zd.y * v2.y + zd.z * v2.z + zd.w * v2.w;
    float p3 = zd.x * v3.x + zd.y * v3.y + zd.z * v3.z + zd.w * v3.w;
#pragma unroll
    for (int off = 16; off > 0; off >>= 1) {
      p0 += __shfl_xor(p0, off);
      p1 += __shfl_xor(p1, off);
      p2 += __shfl_xor(p2, off);
      p3 += __shfl_xor(p3, off);
    }
    if (l == 0) {
      out[csr_eid[k]] = p0;
      out[csr_eid[k + 1]] = p1;
      out[csr_eid[k + 2]] = p2;
      out[csr_eid[k + 3]] = p3;
    }
  }
  for (; k < e; ++k) {
    int j = csr_src[k];
    float4 v = z4[j * 32 + l];
    float p = zd.x * v.x + zd.y * v.y + zd.z * v.z + zd.w * v.w;
#pragma unroll
    for (int off = 16; off > 0; off >>= 1) p += __shfl_xor(p, off);
    if (l == 0) out[csr_eid[k]] = p;
  }
}

extern "C" void kernel_launch(void* const* d_in, const int* in_sizes, int n_in,
                              void* d_out, int out_size, void* d_ws, size_t ws_size,
                              hipStream_t stream) {
  const float* x  = (const float*)d_in[0];
  const int*   ei = (const int*)d_in[1];
  const float* W1 = (const float*)d_in[2];
  const float* b1 = (const float*)d_in[3];
  const float* W2 = (const float*)d_in[4];
  const float* b2 = (const float*)d_in[5];

  const int N = in_sizes[0] / 128;
  const int E = in_sizes[1] / 2;
  const int* src = ei;
  const int* dst = ei + E;

  char* ws = (char*)d_ws;
  size_t off = 0;
  auto alloc = [&](size_t bytes) -> void* {
    void* p = ws + off;
    off += (bytes + 255) & ~(size_t)255;
    return p;
  };
  float* bufA    = (float*)alloc((size_t)N * 128 * 4);
  float* bufB    = (float*)alloc((size_t)N * 128 * 4);
  float* dinv    = (float*)alloc((size_t)N * 4);
  int*   rowptr  = (int*)alloc((size_t)(N + 1) * 4);
  int*   csr_src = (int*)alloc((size_t)E * 4);
  int*   csr_eid = (int*)alloc((size_t)E * 4);
  int*   tmp     = (int*)alloc((size_t)N * 4);
  int*   deg     = (int*)alloc((size_t)N * 4);   // zeroed region starts here
  int*   cnt     = (int*)alloc((size_t)N * 4);
  int*   bsums   = (int*)alloc(1024);
  size_t zbytes = ((char*)bsums + 1024) - (char*)deg;
  hipMemsetAsync(deg, 0, zbytes, stream);

  const int EB = (E + 255) / 256;
  const int NB = (N + 255) / 256;
  const int SB = (N + 511) / 512;

  deg_kernel<<<EB, 256, 0, stream>>>(dst, deg, E);
  scan1_kernel<<<SB, 512, 0, stream>>>(deg, tmp, bsums, N);
  scan2_kernel<<<1, 256, 0, stream>>>(bsums, SB);
  scan3_kernel<<<NB, 256, 0, stream>>>(tmp, bsums, deg, rowptr, dinv, N);
  scatter_kernel<<<EB, 256, 0, stream>>>(src, dst, rowptr, cnt, csr_src, csr_eid, E);

  const int GB = (N + 63) / 64;
  const int AB = (N + 15) / 16;
  const int DB = (N + 7) / 8;

  // layer 1
  gemm_kernel<<<GB, 256, 0, stream>>>(x, W1, dinv, bufA, N);
  agg_kernel<<<AB, 256, 0, stream>>>((const float4*)bufA, dinv, rowptr, csr_src,
                                     (const float4*)b1, (float4*)bufB, 1, N);
  // layer 2
  gemm_kernel<<<GB, 256, 0, stream>>>(bufB, W2, dinv, bufA, N);
  agg_kernel<<<AB, 256, 0, stream>>>((const float4*)bufA, dinv, rowptr, csr_src,
                                     (const float4*)b2, (float4*)bufB, 0, N);
  // decode over dst-CSR
  decode_kernel<<<DB, 256, 0, stream>>>((const float4*)bufB, rowptr, csr_src,
                                        csr_eid, (float*)d_out, N);
}